// Round 16
// baseline (81.536 us; speedup 1.0000x reference)
//
#include <hip/hip_runtime.h>
#include <math.h>

#define N_PTS 8192
#define KNN 16

typedef __attribute__((ext_vector_type(8))) short bf16x8;
typedef __attribute__((ext_vector_type(4))) float f32x4v;

__device__ __forceinline__ unsigned short f2bf(float f)
{
    unsigned u = __float_as_uint(f);
    u = u + 0x7fffu + ((u >> 16) & 1u);       // round-to-nearest-even
    return (unsigned short)(u >> 16);
}
__device__ __forceinline__ unsigned pack2(float a, float b)
{
    return (unsigned)f2bf(a) | ((unsigned)f2bf(b) << 16);
}
__device__ __forceinline__ float bf2f(unsigned short h)
{
    return __uint_as_float((unsigned)h << 16);
}
__device__ __forceinline__ float rfl(float x)   // force block-uniform value to SGPR
{
    return __int_as_float(__builtin_amdgcn_readfirstlane(__float_as_int(x)));
}

// ---------------------------------------------------------------------------
// prep_all: blocks 0..47 pack W{1,2,3}b into MFMA B-frag layout;
// blocks 48..79 build pos4; blocks 80..111 compute v1 (bf16):
// v1[i][c] = b1a[c] + sum_k p[i][k]*(W1a[k][c] + W1a[3+k][c])   (k<3)
// (= pos@W1a_x + pos@W1a_rel + b1a, since x=pos for layer 1).
// ---------------------------------------------------------------------------
__global__ __launch_bounds__(256) void prep_all(
    const float* __restrict__ pos, float4* __restrict__ pos4,
    unsigned short* __restrict__ v1,
    const float* __restrict__ w1a, const float* __restrict__ b1a,
    const float* __restrict__ w1b, const float* __restrict__ w2b,
    const float* __restrict__ w3b,
    uint4* __restrict__ dst)
{
    const int b = blockIdx.x;
    if (b < 48) {
        if (threadIdx.x >= 64) return;
        const float* Ws[3] = {w1b, w2b, w3b};
        const int Kd[3] = {64, 64, 128};
        const int Nd[3] = {64, 64, 128};
        const int start[4] = {0, 8, 16, 48};
        int m = 0;
        while (b >= start[m + 1]) ++m;
        const int f  = b - start[m];
        const int NT = Nd[m] / 16;
        const int ks = f / NT, nt = f % NT;
        const int lane = threadIdx.x;
        const int c  = nt * 16 + (lane & 15);
        const int k0 = ks * 32 + (lane >> 4) * 8;
        const int N = Nd[m];
        const float* W = Ws[m];
        float v[8];
#pragma unroll
        for (int j = 0; j < 8; ++j) v[j] = W[(k0 + j) * N + c];
        uint4 o;
        o.x = pack2(v[0], v[1]); o.y = pack2(v[2], v[3]);
        o.z = pack2(v[4], v[5]); o.w = pack2(v[6], v[7]);
        dst[b * 64 + lane] = o;
    } else if (b < 80) {
        const int i = (b - 48) * 256 + threadIdx.x;
        const float x = pos[i * 3 + 0];
        const float y = pos[i * 3 + 1];
        const float z = pos[i * 3 + 2];
        pos4[i] = make_float4(x, y, z, fmaf(x, x, fmaf(y, y, z * z)));
    } else {
        const int i = (b - 80) * 256 + threadIdx.x;
        const float px = pos[i * 3 + 0], py = pos[i * 3 + 1], pz = pos[i * 3 + 2];
#pragma unroll
        for (int c8 = 0; c8 < 64; c8 += 8) {
            unsigned o[4];
#pragma unroll
            for (int d2 = 0; d2 < 4; ++d2) {
                float r[2];
#pragma unroll
                for (int e = 0; e < 2; ++e) {
                    const int c = c8 + d2 * 2 + e;
                    float acc = b1a[c];
                    acc = fmaf(px, w1a[0 * 64 + c] + w1a[3 * 64 + c], acc);
                    acc = fmaf(py, w1a[1 * 64 + c] + w1a[4 * 64 + c], acc);
                    acc = fmaf(pz, w1a[2 * 64 + c] + w1a[5 * 64 + c], acc);
                    r[e] = acc;
                }
                o[d2] = pack2(r[0], r[1]);
            }
            *reinterpret_cast<uint4*>(v1 + i * 64 + c8) = make_uint4(o[0], o[1], o[2], o[3]);
        }
    }
}

// ---------------------------------------------------------------------------
// kNN threshold-select (R11 kernel verbatim — proven 34us).
// ---------------------------------------------------------------------------
__device__ __forceinline__ unsigned sortkey(const float d2)
{
    unsigned u = __float_as_uint(d2);
    u ^= (unsigned)((int)u >> 31) | 0x80000000u;
    return u;
}
__device__ __forceinline__ float unkey(unsigned k)
{
    const unsigned u = (k & 0x80000000u) ? (k ^ 0x80000000u) : ~k;
    return __uint_as_float(u);
}

constexpr int CAP   = 128;
constexpr int QB    = 16;
constexpr int TILE  = 1024;
constexpr int NTL   = N_PTS / TILE;

__device__ __forceinline__ void stage_tile(const float4* src, float4* dst)
{
    __builtin_amdgcn_global_load_lds(
        (const __attribute__((address_space(1))) void*)src,
        (__attribute__((address_space(3))) void*)dst, 16, 0, 0);
}

__global__ __launch_bounds__(512) void knn_kernel(const float4* __restrict__ pos4,
                                                  int* __restrict__ idx_out)
{
    __shared__ float4 tile[2][TILE];
    __shared__ unsigned minkey[QB][64];
    __shared__ float Ts[QB];
    __shared__ unsigned long long surv[QB][CAP];
    __shared__ int scnt[QB];

    const int tid   = threadIdx.x;
    const int w     = tid >> 6;
    const int lane  = tid & 63;
    const int qbase = blockIdx.x * QB;

    if (tid < QB) scnt[tid] = 0;
    reinterpret_cast<unsigned*>(minkey)[tid]       = 0xFFFFFFFFu;
    reinterpret_cast<unsigned*>(minkey)[tid + 512] = 0xFFFFFFFFu;

    float qx[QB], qy[QB], qz[QB];
#pragma unroll
    for (int qi = 0; qi < QB; ++qi) {
        const float4 qp = pos4[qbase + qi];
        qx[qi] = rfl(-2.0f * qp.x);
        qy[qi] = rfl(-2.0f * qp.y);
        qz[qi] = rfl(-2.0f * qp.z);
    }

    const float4* src = pos4 + w * 128 + lane;
    float4* dst0 = &tile[0][w * 128];
    float4* dst1 = &tile[1][w * 128];

    float mn[QB];
#pragma unroll
    for (int qi = 0; qi < QB; ++qi) mn[qi] = 1e30f;

    stage_tile(src,      dst0);
    stage_tile(src + 64, dst0 + 64);
    __syncthreads();
#pragma unroll 1
    for (int t = 0; t < NTL - 1; ++t) {
        float4* nd = (t & 1) ? dst0 : dst1;
        stage_tile(src + (t + 1) * TILE,      nd);
        stage_tile(src + (t + 1) * TILE + 64, nd + 64);
        asm volatile("s_waitcnt vmcnt(2)" ::: "memory");
        __builtin_amdgcn_sched_barrier(0);
        const float4 p0 = tile[t & 1][w * 128 + lane];
        const float4 p1 = tile[t & 1][w * 128 + 64 + lane];
#pragma unroll
        for (int qi = 0; qi < QB; ++qi) {
            const float s0 = fmaf(qx[qi], p0.x, fmaf(qy[qi], p0.y, fmaf(qz[qi], p0.z, p0.w)));
            const float s1 = fmaf(qx[qi], p1.x, fmaf(qy[qi], p1.y, fmaf(qz[qi], p1.z, p1.w)));
            mn[qi] = fminf(mn[qi], fminf(s0, s1));
        }
    }
    {
        asm volatile("s_waitcnt vmcnt(0)" ::: "memory");
        __builtin_amdgcn_sched_barrier(0);
        const int t = NTL - 1;
        const float4 p0 = tile[t & 1][w * 128 + lane];
        const float4 p1 = tile[t & 1][w * 128 + 64 + lane];
#pragma unroll
        for (int qi = 0; qi < QB; ++qi) {
            const float s0 = fmaf(qx[qi], p0.x, fmaf(qy[qi], p0.y, fmaf(qz[qi], p0.z, p0.w)));
            const float s1 = fmaf(qx[qi], p1.x, fmaf(qy[qi], p1.y, fmaf(qz[qi], p1.z, p1.w)));
            mn[qi] = fminf(mn[qi], fminf(s0, s1));
        }
    }
#pragma unroll
    for (int qi = 0; qi < QB; ++qi) atomicMin(&minkey[qi][lane], sortkey(mn[qi]));
    __syncthreads();

#pragma unroll
    for (int k = 0; k < 2; ++k) {
        const int q = w * 2 + k;
        unsigned v = minkey[q][lane];
#pragma unroll
        for (int kk = 2; kk <= 64; kk <<= 1)
#pragma unroll
            for (int j = kk >> 1; j > 0; j >>= 1) {
                const unsigned o = __shfl_xor(v, j);
                const bool up = ((lane & kk) == 0);
                const bool lo = ((lane & j) == 0);
                v = (up == lo) ? min(v, o) : max(v, o);
            }
        if (lane == 15) Ts[q] = unkey(v);
    }
    __syncthreads();

    float T[QB];
#pragma unroll
    for (int qi = 0; qi < QB; ++qi) T[qi] = rfl(Ts[qi]);

    stage_tile(src,      dst0);
    stage_tile(src + 64, dst0 + 64);
#pragma unroll 1
    for (int t = 0; t < NTL - 1; ++t) {
        float4* nd = (t & 1) ? dst0 : dst1;
        stage_tile(src + (t + 1) * TILE,      nd);
        stage_tile(src + (t + 1) * TILE + 64, nd + 64);
        asm volatile("s_waitcnt vmcnt(2)" ::: "memory");
        __builtin_amdgcn_sched_barrier(0);
#pragma unroll
        for (int u = 0; u < 2; ++u) {
            const float4 p = tile[t & 1][w * 128 + u * 64 + lane];
            const int j = t * TILE + w * 128 + u * 64 + lane;
#pragma unroll
            for (int qi = 0; qi < QB; ++qi) {
                const float s = fmaf(qx[qi], p.x, fmaf(qy[qi], p.y, fmaf(qz[qi], p.z, p.w)));
                if (s <= T[qi]) {
                    const int slot = atomicAdd(&scnt[qi], 1);
                    if (slot < CAP)
                        surv[qi][slot] = ((unsigned long long)sortkey(s) << 32) | (unsigned)j;
                }
            }
        }
    }
    {
        asm volatile("s_waitcnt vmcnt(0)" ::: "memory");
        __builtin_amdgcn_sched_barrier(0);
        const int t = NTL - 1;
#pragma unroll
        for (int u = 0; u < 2; ++u) {
            const float4 p = tile[t & 1][w * 128 + u * 64 + lane];
            const int j = t * TILE + w * 128 + u * 64 + lane;
#pragma unroll
            for (int qi = 0; qi < QB; ++qi) {
                const float s = fmaf(qx[qi], p.x, fmaf(qy[qi], p.y, fmaf(qz[qi], p.z, p.w)));
                if (s <= T[qi]) {
                    const int slot = atomicAdd(&scnt[qi], 1);
                    if (slot < CAP)
                        surv[qi][slot] = ((unsigned long long)sortkey(s) << 32) | (unsigned)j;
                }
            }
        }
    }
    __syncthreads();

#pragma unroll
    for (int k = 0; k < 2; ++k) {
        const int q = w * 2 + k;
        const int n = min(scnt[q], CAP);
        const unsigned long long k0 = (lane < n) ? surv[q][lane] : ~0ull;
        const unsigned long long k1 = (lane + 64 < n) ? surv[q][lane + 64] : ~0ull;
        int r0 = 0, r1 = 0;
        for (int e = 0; e < n; ++e) {
            const unsigned long long ke = surv[q][e];
            r0 += (ke < k0) ? 1 : 0;
            r1 += (ke < k1) ? 1 : 0;
        }
        if (lane < n && r0 < KNN)
            idx_out[(qbase + q) * KNN + r0] = (int)(unsigned)(k0 & 0xFFFFFFFFu);
        if (lane + 64 < n && r1 < KNN)
            idx_out[(qbase + q) * KNN + r1] = (int)(unsigned)(k1 & 0xFFFFFFFFu);
    }
}

// ---------------------------------------------------------------------------
// conv_fused: PointNetConv WITHOUT per-edge GEMM1.
// h_ij = relu(v_j - u_i), v precomputed per point (bf16, includes +ba and
// the p_j@Wa_rel term), u_i = p_i@Wa_rel computed in-kernel into LDS.
// Then GEMM2 (MFMA) + max-aggregate + relu, as before.
// VNEXT>0: epilogue computes v_next for this block's 8 points:
// v_next[i][c] = bnext[c] + sum_k h_out[i][k]*Wnext[k][c]
//             + sum_d p[i][d]*Wnext[64+d][c]   (h_out re-read from LDS).
// ---------------------------------------------------------------------------
template <int CMID, int COUT, int WM, int WN, int VNEXT>
__global__ __launch_bounds__(256) void conv_fused(
    const unsigned short* __restrict__ v, const float* __restrict__ pos,
    const int* __restrict__ idx,
    const float* __restrict__ WaRel,            // 3 x CMID (rows CIN..CIN+2 of Wa)
    const uint4* __restrict__ fB, const float* __restrict__ bb,
    const float* __restrict__ Wnext, const float* __restrict__ bnext,
    float* __restrict__ out, unsigned short* __restrict__ vout)
{
    constexpr int PB  = 8, M = 128;
    constexpr int KP2 = CMID + 8;
    constexpr int KS2 = CMID / 32;
    constexpr int NT  = COUT / 16;
    constexpr int NTW = NT / WN;
    constexpr int MFW = (M / 16) / WM;

    __shared__ int nbr[M];
    __shared__ float ubuf[PB][CMID];
    __shared__ __align__(16) unsigned short hbuf[M * KP2];

    const int tid  = threadIdx.x;
    const int lane = tid & 63;
    const int w    = tid >> 6;
    const int wm   = w / WN, wn = w % WN;
    const int i0   = blockIdx.x * PB;

    if (tid < M) nbr[tid] = idx[i0 * KNN + tid];
    // u_i = p_i @ Wa_rel into LDS (8 x CMID)
    for (int e = tid; e < PB * CMID; e += 256) {
        const int pt = e / CMID, c = e % CMID;
        float u = pos[(i0 + pt) * 3 + 0] * WaRel[c];
        u = fmaf(pos[(i0 + pt) * 3 + 1], WaRel[CMID + c], u);
        u = fmaf(pos[(i0 + pt) * 3 + 2], WaRel[2 * CMID + c], u);
        ubuf[pt][c] = u;
    }
    __syncthreads();

    // h rows: gather v_j, subtract u_i, relu, store bf16 to hbuf
    {
        const int row = tid >> 1, hh = tid & 1;
        const int j = nbr[row], pt = row >> 4;
        const int cb = hh * (CMID / 2);
#pragma unroll
        for (int cc = 0; cc < CMID / 2; cc += 8) {
            const uint4 vv = *reinterpret_cast<const uint4*>(v + j * CMID + cb + cc);
            const unsigned dw[4] = {vv.x, vv.y, vv.z, vv.w};
            unsigned o[4];
#pragma unroll
            for (int d2 = 0; d2 < 4; ++d2) {
                const int c = cb + cc + d2 * 2;
                const float flo = __uint_as_float(dw[d2] << 16);
                const float fhi = __uint_as_float(dw[d2] & 0xffff0000u);
                const float rlo = fmaxf(flo - ubuf[pt][c],     0.0f);
                const float rhi = fmaxf(fhi - ubuf[pt][c + 1], 0.0f);
                o[d2] = pack2(rlo, rhi);
            }
            *reinterpret_cast<uint4*>(&hbuf[row * KP2 + cb + cc]) =
                make_uint4(o[0], o[1], o[2], o[3]);
        }
    }
    __syncthreads();

    // GEMM2: out = relu(max_k(htile @ Wb) + bb)
    float outv[MFW][NTW];
    {
        uint4 b2[KS2][NTW];
#pragma unroll
        for (int ks = 0; ks < KS2; ++ks)
#pragma unroll
            for (int nt = 0; nt < NTW; ++nt)
                b2[ks][nt] = fB[(ks * NT + wn * NTW + nt) * 64 + lane];

        f32x4v acc2[MFW][NTW];
#pragma unroll
        for (int mf = 0; mf < MFW; ++mf)
#pragma unroll
            for (int nt = 0; nt < NTW; ++nt) acc2[mf][nt] = (f32x4v)0.0f;

#pragma unroll
        for (int mf = 0; mf < MFW; ++mf) {
            bf16x8 a[KS2];
#pragma unroll
            for (int ks = 0; ks < KS2; ++ks)
                a[ks] = *reinterpret_cast<const bf16x8*>(
                    &hbuf[((wm * MFW + mf) * 16 + (lane & 15)) * KP2 + ks * 32 + (lane >> 4) * 8]);
#pragma unroll
            for (int nt = 0; nt < NTW; ++nt)
#pragma unroll
                for (int ks = 0; ks < KS2; ++ks)
                    acc2[mf][nt] = __builtin_amdgcn_mfma_f32_16x16x32_bf16(
                        a[ks], __builtin_bit_cast(bf16x8, b2[ks][nt]), acc2[mf][nt], 0, 0, 0);
        }

        float bbv[NTW];
#pragma unroll
        for (int nt = 0; nt < NTW; ++nt) bbv[nt] = bb[(wn * NTW + nt) * 16 + (lane & 15)];

#pragma unroll
        for (int mf = 0; mf < MFW; ++mf)
#pragma unroll
            for (int nt = 0; nt < NTW; ++nt) {
                const f32x4v t = acc2[mf][nt];
                float m0 = fmaxf(fmaxf(t[0], t[1]), fmaxf(t[2], t[3]));
                m0 = fmaxf(m0, __shfl_xor(m0, 16));
                m0 = fmaxf(m0, __shfl_xor(m0, 32));
                outv[mf][nt] = fmaxf(m0 + bbv[nt], 0.0f);
            }
    }
    __syncthreads();   // all hbuf reads (a-frags) complete before overwrite

    // write out; stash out rows (8 x COUT) in hbuf rows 0..7 for vnext
#pragma unroll
    for (int mf = 0; mf < MFW; ++mf)
#pragma unroll
        for (int nt = 0; nt < NTW; ++nt) {
            if (lane < 16) {
                const int pt = wm * MFW + mf;
                const int c  = (wn * NTW + nt) * 16 + lane;
                out[(i0 + pt) * COUT + c] = outv[mf][nt];
                if constexpr (VNEXT > 0) hbuf[pt * KP2 + c] = f2bf(outv[mf][nt]);
            }
        }

    if constexpr (VNEXT > 0) {
        __syncthreads();
        constexpr int CPT = VNEXT / 32;          // cols per thread (2 or 4)
        const int pt = tid >> 5;
        const int c0 = (tid & 31) * CPT;
        float acc[CPT];
#pragma unroll
        for (int e = 0; e < CPT; ++e) acc[e] = bnext[c0 + e];
        for (int k = 0; k < COUT; ++k) {
            const float hk = bf2f(hbuf[pt * KP2 + k]);
#pragma unroll
            for (int e = 0; e < CPT; ++e)
                acc[e] = fmaf(hk, Wnext[k * VNEXT + c0 + e], acc[e]);
        }
#pragma unroll
        for (int d = 0; d < 3; ++d) {
            const float pd = pos[(i0 + pt) * 3 + d];
#pragma unroll
            for (int e = 0; e < CPT; ++e)
                acc[e] = fmaf(pd, Wnext[(COUT + d) * VNEXT + c0 + e], acc[e]);
        }
        if constexpr (CPT == 2) {
            *reinterpret_cast<unsigned*>(vout + (i0 + pt) * VNEXT + c0) = pack2(acc[0], acc[1]);
        } else {
            uint2 o;
            o.x = pack2(acc[0], acc[1]);
            o.y = pack2(acc[2], acc[3]);
            *reinterpret_cast<uint2*>(vout + (i0 + pt) * VNEXT + c0) = o;
        }
    }
}

extern "C" void kernel_launch(void* const* d_in, const int* in_sizes, int n_in,
                              void* d_out, int out_size, void* d_ws, size_t ws_size,
                              hipStream_t stream)
{
    const float* pos = (const float*)d_in[0];
    const float* W1a = (const float*)d_in[1];
    const float* b1a = (const float*)d_in[2];
    const float* W1b = (const float*)d_in[3];
    const float* b1b = (const float*)d_in[4];
    const float* W2a = (const float*)d_in[5];
    const float* b2a = (const float*)d_in[6];
    const float* W2b = (const float*)d_in[7];
    const float* b2b = (const float*)d_in[8];
    const float* W3a = (const float*)d_in[9];
    const float* b3a = (const float*)d_in[10];
    const float* W3b = (const float*)d_in[11];
    const float* b3b = (const float*)d_in[12];

    float* out = (float*)d_out;
    float* h1 = out;                        // 8192 x 64
    float* h2 = out + N_PTS * 64;           // 8192 x 64
    float* h3 = out + N_PTS * 128;          // 8192 x 128

    // workspace: idx (512K) | Wb frags (48K) | v3 (2MB bf16)
    int*            idx     = (int*)d_ws;
    uint4*          wsFrags = (uint4*)((char*)d_ws + 524288);
    unsigned short* v3      = (unsigned short*)((char*)d_ws + 589824);

    // h3 region (dead until conv3): pos4 (128K) | v1 (1MB) | v2 (1MB)
    float4*         pos4 = (float4*)h3;
    unsigned short* v1   = (unsigned short*)((char*)h3 + 131072);
    unsigned short* v2   = (unsigned short*)((char*)h3 + 1179648);

    prep_all<<<112, 256, 0, stream>>>(pos, pos4, v1, W1a, b1a, W1b, W2b, W3b, wsFrags);
    knn_kernel<<<N_PTS / QB, 512, 0, stream>>>(pos4, idx);

    const uint4* fW1b = wsFrags + 0 * 64;
    const uint4* fW2b = wsFrags + 8 * 64;
    const uint4* fW3b = wsFrags + 16 * 64;

    // conv1: h1 = relu(max(relu(v1_j - u1_i) @ W1b) + b1b); epilogue -> v2
    conv_fused<64, 64, 4, 1, 64><<<N_PTS / 8, 256, 0, stream>>>(
        v1, pos, idx, W1a + 3 * 64, fW1b, b1b, W2a, b2a, h1, v2);
    // conv2: -> h2; epilogue -> v3
    conv_fused<64, 64, 4, 1, 128><<<N_PTS / 8, 256, 0, stream>>>(
        v2, pos, idx, W2a + 64 * 64, fW2b, b2b, W3a, b3a, h2, v3);
    // conv3: -> h3
    conv_fused<128, 128, 2, 2, 0><<<N_PTS / 8, 256, 0, stream>>>(
        v3, pos, idx, W3a + 64 * 128, fW3b, b3b, nullptr, nullptr, h3, nullptr);
}